// Round 1
// baseline (220.202 us; speedup 1.0000x reference)
//
#include <hip/hip_runtime.h>

// De-emphasis IIR: y[n] = x[n] + C*y[n-1] per row, 64 rows of 480000 fp32.
//
// R5 structure (post-mortem of R4's 75 us/dispatch = ~55% of the ~42 us
// roofline): counters showed HBM 20-32%, VALU 11%, occupancy 65% -> latency/
// barrier-drain bound, not BW bound. R4 paid a full vmcnt(0) drain at every
// __syncthreads with zero load/compute overlap. R5:
//   - each block walks TILES=8 tiles of SPAN=2048 down the row, EXACT carry
//     across tiles in registers -> halo (512) only at block start
//     (fetch overhead 14.3% -> 3.3%); grid 31x64=1984 blocks, all resident.
//   - double-buffered LDS (2 x 8 KiB) staged by global_load_lds DMA (16B,
//     no VGPR round-trip); linear LDS dest + pre-swizzled global source
//     (involution p ^ ((p>>3)&1), conflict-free for the 2-chunk/thread
//     segment reads and linear phase-D reads).
//   - raw s_barrier + counted "s_waitcnt vmcnt(2)" (allow 2 D-stores in
//     flight, retire the 2 stage loads) -> next tile's DMA stays in flight
//     across all 3 barriers of the current tile. NO __syncthreads anywhere.
//   - wave scan: A is lane-constant (CSEG^lane) -> B-only shfl scan,
//     6 shfl + 6 fma with constexpr factors.
// Cross-block carry: 512-elem halo; 0.97^512 ~ 1.7e-7 (validated in R1-R4:
// absmax 0.0625 = fp32 association noise, threshold 0.4475).

#define COEFF 0.97f
#define ROW_LEN 480000
#define SEG 8                            // elements per thread per tile
#define BLOCK 256                        // threads per block (4 waves)
#define WAVES (BLOCK / 64)
#define HALO 512
#define SPAN (BLOCK * SEG)               // 2048 elements per tile
#define TILES 8
#define OUT_PER_BLOCK (TILES * SPAN - HALO)  // 15872
#define BLOCKS_PER_ROW ((ROW_LEN + OUT_PER_BLOCK - 1) / OUT_PER_BLOCK)  // 31
#define CHUNKS (SPAN / 4)                // 512 float4 chunks per tile
#define CPT (SEG / 4)                    // 2 chunks per thread segment
#define K_ITERS (CHUNKS / BLOCK)         // 2 staging/store chunks per thread

typedef float v4f __attribute__((ext_vector_type(4)));

constexpr float fpow(float b, int n) {
    float r = 1.0f;
    for (int i = 0; i < n; ++i) r *= b;
    return r;
}
constexpr float CSEG  = fpow(COEFF, SEG);        // 0.97^8
constexpr float CWAVE = fpow(COEFF, 64 * SEG);   // 0.97^512 ~ 1.65e-7
// shfl-scan factors: CSEG^(2^s)
constexpr float WF0 = fpow(COEFF, SEG * 1);
constexpr float WF1 = fpow(COEFF, SEG * 2);
constexpr float WF2 = fpow(COEFF, SEG * 4);
constexpr float WF3 = fpow(COEFF, SEG * 8);
constexpr float WF4 = fpow(COEFF, SEG * 16);
constexpr float WF5 = fpow(COEFF, SEG * 32);

struct Pows { float p[SEG + 1]; };
constexpr Pows make_pows() {
    Pows P{};
    float r = 1.0f;
    for (int i = 0; i <= SEG; ++i) { P.p[i] = r; r *= COEFF; }
    return P;
}
constexpr Pows PW = make_pows();   // PW.p[i] = COEFF^i

// Involution chunk swizzle: physical slot p holds global chunk p^((p>>3)&1).
// Phase-B reads (thread t reads chunks 2t,2t+1) hit all 8 bank-quads per
// 8-lane group; phase-D linear reads are trivially conflict-free; the DMA's
// linear LDS writes are conflict-free; the global source is permuted only in
// 16B pairs within 128B lines -> coalescing preserved.
__device__ __forceinline__ int swz(int m) { return m ^ ((m >> 3) & 1); }

#define GLOAD_LDS(gp, lp)                                                     \
    __builtin_amdgcn_global_load_lds(                                         \
        (const __attribute__((address_space(1))) void*)(gp),                  \
        (__attribute__((address_space(3))) void*)(lp), 16, 0, 0)

// Stage one 2048-elem tile into dstbuf. Interior tiles: pure DMA (uniform
// branch, no per-lane predicate). Edge tiles (block-0 halo, row tail):
// VGPR-staged with zero fill (~1.4% of tiles).
__device__ __forceinline__ void stage_tile(const float* __restrict__ xrow,
                                           v4f* dstbuf, int tbase,
                                           int t, int wave) {
    if (tbase >= 0 && tbase + SPAN <= ROW_LEN) {
        #pragma unroll
        for (int k = 0; k < K_ITERS; ++k) {
            const int p  = k * BLOCK + t;        // this lane's physical chunk
            const int gc = swz(p);               // source global chunk
            v4f* dst = dstbuf + (k * BLOCK + (wave << 6));  // wave-uniform base
            GLOAD_LDS(xrow + tbase + 4 * gc, dst);          // + lane*16 implicit
        }
    } else {
        #pragma unroll
        for (int k = 0; k < K_ITERS; ++k) {
            const int p  = k * BLOCK + t;
            const int gc = swz(p);
            const int e  = tbase + 4 * gc;
            v4f v = {0.0f, 0.0f, 0.0f, 0.0f};
            if (e >= 0 && e < ROW_LEN) v = *(const v4f*)(xrow + e);
            dstbuf[p] = v;
        }
    }
}

__global__ __launch_bounds__(BLOCK) void deemph_kernel(const float* __restrict__ x,
                                                       float* __restrict__ y) {
    __shared__ v4f buf[2][CHUNKS];     // 2 x 8 KiB double buffer
    __shared__ float ws[WAVES];

    const int row  = blockIdx.y;
    const int blk  = blockIdx.x;
    const int t    = threadIdx.x;
    const int lane = t & 63;
    const int wave = t >> 6;

    const float* __restrict__ xrow = x + (long long)row * ROW_LEN;
    float* __restrict__ yrow       = y + (long long)row * ROW_LEN;

    const int span_start = blk * OUT_PER_BLOCK - HALO;
    const int out_lo     = blk * OUT_PER_BLOCK;   // first element this block owns

    // Aex = CSEG^lane, exact bit-product (loop-invariant across tiles)
    float Aex = 1.0f;
    if (lane & 1)  Aex *= WF0;
    if (lane & 2)  Aex *= WF1;
    if (lane & 4)  Aex *= WF2;
    if (lane & 8)  Aex *= WF3;
    if (lane & 16) Aex *= WF4;
    if (lane & 32) Aex *= WF5;

    // ---- prologue: stage tile 0 into buf[0], drain fully once ----
    stage_tile(xrow, &buf[0][0], span_start, t, wave);
    asm volatile("s_waitcnt vmcnt(0) lgkmcnt(0)" ::: "memory");

    float CB = 0.0f;   // carry: y at last element of previous tile (0 = halo start)

    #pragma unroll
    for (int tt = 0; tt < TILES; ++tt) {
        const int cur = tt & 1;
        const int tile_base = span_start + tt * SPAN;

        // bar1: tile tt resident in buf[cur] for all waves (each wave counted
        // its own DMA via vmcnt before arriving). Also: every wave is past its
        // phase-D reads of tile tt-1 -> buf[cur^1] is free to restage.
        __builtin_amdgcn_s_barrier();
        asm volatile("" ::: "memory");

        if (tt + 1 < TILES)
            stage_tile(xrow, &buf[cur ^ 1][0], tile_base + SPAN, t, wave);

        // ---- B: read own contiguous 8-elem segment (swizzled slots) ----
        float l[SEG];
        #pragma unroll
        for (int c = 0; c < CPT; ++c) {
            v4f v = buf[cur][swz(CPT * t + c)];
            l[4*c+0] = v.x; l[4*c+1] = v.y; l[4*c+2] = v.z; l[4*c+3] = v.w;
        }
        // local inclusive scan (zero carry-in)
        #pragma unroll
        for (int i = 1; i < SEG; ++i) l[i] = fmaf(COEFF, l[i-1], l[i]);

        // ---- wave scan on B only (A is lane-constant) ----
        float Bv = l[SEG-1];
        {
            float Bp;
            Bp = __shfl_up(Bv, 1);  if (lane >= 1)  Bv = fmaf(WF0, Bp, Bv);
            Bp = __shfl_up(Bv, 2);  if (lane >= 2)  Bv = fmaf(WF1, Bp, Bv);
            Bp = __shfl_up(Bv, 4);  if (lane >= 4)  Bv = fmaf(WF2, Bp, Bv);
            Bp = __shfl_up(Bv, 8);  if (lane >= 8)  Bv = fmaf(WF3, Bp, Bv);
            Bp = __shfl_up(Bv, 16); if (lane >= 16) Bv = fmaf(WF4, Bp, Bv);
            Bp = __shfl_up(Bv, 32); if (lane >= 32) Bv = fmaf(WF5, Bp, Bv);
        }
        float Bex = __shfl_up(Bv, 1);
        if (lane == 0) Bex = 0.0f;
        if (lane == 63) ws[wave] = Bv;

        // bar2: ws visible
        asm volatile("s_waitcnt lgkmcnt(0)" ::: "memory");
        __builtin_amdgcn_s_barrier();
        asm volatile("" ::: "memory");

        // carry into this wave: CB decayed over earlier waves + their sums
        float Cw = CB;
        #pragma unroll
        for (int v = 0; v < WAVES - 1; ++v)
            if (v < wave) Cw = fmaf(CWAVE, Cw, ws[v]);
        const float K = fmaf(Aex, Cw, Bex);   // y just before this segment
        #pragma unroll
        for (int i = 0; i < SEG; ++i) l[i] = fmaf(K, PW.p[i + 1], l[i]);

        // exact block carry for next tile (all threads redundantly)
        #pragma unroll
        for (int v = 0; v < WAVES; ++v) CB = fmaf(CWAVE, CB, ws[v]);

        // ---- C: write back own slots (same slots this thread read) ----
        #pragma unroll
        for (int c = 0; c < CPT; ++c) {
            v4f v;
            v.x = l[4*c+0]; v.y = l[4*c+1]; v.z = l[4*c+2]; v.w = l[4*c+3];
            buf[cur][swz(CPT * t + c)] = v;
        }

        // bar3: C visible
        asm volatile("s_waitcnt lgkmcnt(0)" ::: "memory");
        __builtin_amdgcn_s_barrier();
        asm volatile("" ::: "memory");

        // ---- D: coalesced stores (skip halo, clamp row end) ----
        #pragma unroll
        for (int k = 0; k < K_ITERS; ++k) {
            const int p = k * BLOCK + t;
            const int e = tile_base + 4 * swz(p);
            v4f v = buf[cur][p];
            if (e >= out_lo && e < ROW_LEN)
                *(v4f*)(yrow + e) = v;
        }

        // retire the K_ITERS=2 stage loads for tile tt+1; leave the 2 newest
        // (this tile's D stores) in flight. Never vmcnt(0) in the loop.
        if (tt + 1 < TILES)
            asm volatile("s_waitcnt vmcnt(2)" ::: "memory");
    }
}

extern "C" void kernel_launch(void* const* d_in, const int* in_sizes, int n_in,
                              void* d_out, int out_size, void* d_ws, size_t ws_size,
                              hipStream_t stream) {
    (void)n_in; (void)d_ws; (void)ws_size; (void)out_size;
    const float* x = (const float*)d_in[0];
    float* y = (float*)d_out;
    const int n_rows = in_sizes[0] / ROW_LEN;  // 64 for (32,2,480000)
    dim3 grid(BLOCKS_PER_ROW, n_rows);
    deemph_kernel<<<grid, BLOCK, 0, stream>>>(x, y);
}

// Round 2
// 217.392 us; speedup vs baseline: 1.0129x; 1.0129x over previous
//
#include <hip/hip_runtime.h>

// De-emphasis IIR: y[n] = x[n] + C*y[n-1] per row, 64 rows of 480000 fp32.
//
// R6 structure (post-mortem of R4/R5, both ~75-78 us at <30% HBM, <12% VALU,
// ~56-65% occupancy -> NOTHING saturated): the shared bottleneck was the
// block itself -- 4 waves lockstepped through 3 barriers per tile, only ~8
// independent barrier-synced contexts per CU, per-tile critical path fully
// exposed. R6 deletes the block structure entirely:
//
//   SEG=4: lane i holds elements 4i..4i+3 -> ONE float4 per lane is both
//   perfectly coalesced (64 lanes x 16B = 1KB contiguous) AND the layout the
//   scan needs. No LDS transpose. No LDS. No barriers. Each WAVE is an
//   independent scanner over its own row span:
//     - register prefetch ring (PF=3 passes in flight)
//     - per-pass: 3-fma local scan, 6-shfl lane-constant affine wave scan
//       (A = C^4 per lane is lane-invariant per step -> B-only scan with
//       constexpr factors), exclusive shfl, lane-63 broadcast
//     - cross-pass serial dependency is ONE fma: c = fma(c, C^256, B63);
//       raw scans of consecutive passes are independent -> pipeline freely
//   Grid: 118 waves/row x 64 rows = 7552 active waves (~30/CU, ~7.5/SIMD)
//   of fully independent work, vs ~8 lockstepped blocks/CU before.
//
// Cross-wave carry: 512-elem halo (2 passes); 0.97^512 ~ 1.7e-7 (validated
// R1-R5: absmax 0.0625 = fp32 association noise, threshold 0.4475).
// ROW_LEN % 256 == 0 -> every pass is wholly in or out of the row; all
// load/store predicates are wave-uniform, shfls sit in convergent code.

#define COEFF 0.97f
#define ROW_LEN 480000
#define HALO 512
#define SPAN_W 256                         // elems per wave per pass (64*4)
#define P_HALO (HALO / SPAN_W)             // 2
#define P_OUT 16
#define P_TOT (P_OUT + P_HALO)             // 18
#define OUT_W (P_OUT * SPAN_W)             // 4096 output elems per wave
#define WPR ((ROW_LEN + OUT_W - 1) / OUT_W) // 118 waves per row
#define BLOCK 256
#define WAVES (BLOCK / 64)
#define PF 3                               // prefetch depth (passes in regs)

typedef float v4f __attribute__((ext_vector_type(4)));

constexpr float fpow(float b, int n) {
    float r = 1.0f;
    for (int i = 0; i < n; ++i) r *= b;
    return r;
}
// wave-scan step factors: C^(4*2^k)
constexpr float W4   = fpow(COEFF, 4);
constexpr float W8   = fpow(COEFF, 8);
constexpr float W16  = fpow(COEFF, 16);
constexpr float W32  = fpow(COEFF, 32);
constexpr float W64  = fpow(COEFF, 64);
constexpr float W128 = fpow(COEFF, 128);
constexpr float W256 = fpow(COEFF, 256);   // per-pass carry decay
constexpr float C1P  = fpow(COEFF, 1);
constexpr float C2P  = fpow(COEFF, 2);
constexpr float C3P  = fpow(COEFF, 3);
constexpr float C4P  = fpow(COEFF, 4);

__global__ __launch_bounds__(BLOCK, 8) void deemph_kernel(const float* __restrict__ x,
                                                          float* __restrict__ y) {
    const int lane = threadIdx.x & 63;
    const int wave = threadIdx.x >> 6;
    const int widx = blockIdx.x * WAVES + wave;
    if (widx >= WPR) return;               // wave-uniform; no barriers anywhere
    const int row  = blockIdx.y;

    const float* __restrict__ xrow = x + (long long)row * ROW_LEN;
    float* __restrict__ yrow       = y + (long long)row * ROW_LEN;

    // lane's element base for pass 0 (may be <0 in the leading halo)
    const int le = widx * OUT_W - HALO + 4 * lane;

    // Aex = C^(4*lane): exact bit-product, loop-invariant
    float Aex = 1.0f;
    if (lane & 1)  Aex *= W4;
    if (lane & 2)  Aex *= W8;
    if (lane & 4)  Aex *= W16;
    if (lane & 8)  Aex *= W32;
    if (lane & 16) Aex *= W64;
    if (lane & 32) Aex *= W128;

    // ---- prefetch ring: PF passes in flight in registers ----
    v4f r[PF];
    #pragma unroll
    for (int p = 0; p < PF; ++p) {
        const int e = le + p * SPAN_W;
        v4f v = {0.0f, 0.0f, 0.0f, 0.0f};
        if (e >= 0 && e < ROW_LEN) v = *(const v4f*)(xrow + e);
        r[p] = v;
    }

    float c = 0.0f;   // carry: y at element just before current pass
    #pragma unroll
    for (int p = 0; p < P_TOT; ++p) {
        v4f v = r[p % PF];                 // static index after full unroll
        if (p + PF < P_TOT) {
            const int e2 = le + (p + PF) * SPAN_W;
            v4f nv = {0.0f, 0.0f, 0.0f, 0.0f};
            if (e2 >= 0 && e2 < ROW_LEN) nv = *(const v4f*)(xrow + e2);
            r[p % PF] = nv;
        }

        // local inclusive scan (zero carry-in; carry folded at the end)
        const float l0 = v.x;
        const float l1 = fmaf(COEFF, l0, v.y);
        const float l2 = fmaf(COEFF, l1, v.z);
        const float l3 = fmaf(COEFF, l2, v.w);

        // wave inclusive scan on segment sums (A lane-constant per step)
        float Bv = l3, Bp;
        Bp = __shfl_up(Bv, 1);  if (lane >= 1)  Bv = fmaf(W4,   Bp, Bv);
        Bp = __shfl_up(Bv, 2);  if (lane >= 2)  Bv = fmaf(W8,   Bp, Bv);
        Bp = __shfl_up(Bv, 4);  if (lane >= 4)  Bv = fmaf(W16,  Bp, Bv);
        Bp = __shfl_up(Bv, 8);  if (lane >= 8)  Bv = fmaf(W32,  Bp, Bv);
        Bp = __shfl_up(Bv, 16); if (lane >= 16) Bv = fmaf(W64,  Bp, Bv);
        Bp = __shfl_up(Bv, 32); if (lane >= 32) Bv = fmaf(W128, Bp, Bv);
        float Bex = __shfl_up(Bv, 1);
        if (lane == 0) Bex = 0.0f;
        const float B63 = __shfl(Bv, 63);  // wave total (raw, no carry)

        // fold running carry into this thread; advance carry (1 fma chain)
        const float Kt = fmaf(c, Aex, Bex);
        c = fmaf(c, W256, B63);

        if (p >= P_HALO) {
            const int e = le + p * SPAN_W;
            if (e < ROW_LEN) {
                v4f o;
                o.x = fmaf(Kt, C1P, l0);
                o.y = fmaf(Kt, C2P, l1);
                o.z = fmaf(Kt, C3P, l2);
                o.w = fmaf(Kt, C4P, l3);
                *(v4f*)(yrow + e) = o;
            }
        }
    }
}

extern "C" void kernel_launch(void* const* d_in, const int* in_sizes, int n_in,
                              void* d_out, int out_size, void* d_ws, size_t ws_size,
                              hipStream_t stream) {
    (void)n_in; (void)d_ws; (void)ws_size; (void)out_size;
    const float* x = (const float*)d_in[0];
    float* y = (float*)d_out;
    const int n_rows = in_sizes[0] / ROW_LEN;  // 64 for (32,2,480000)
    dim3 grid((WPR + WAVES - 1) / WAVES, n_rows);
    deemph_kernel<<<grid, BLOCK, 0, stream>>>(x, y);
}